// Round 7
// baseline (115.757 us; speedup 1.0000x reference)
//
#include <hip/hip_runtime.h>

// DistNet: out[n] = sigmoid((min_p ||x_n - p||^2 + alpha) / beta)
// beta = softplus(beta_raw), alpha = -beta*ln(1000)
// x: [65536,128] f32, points: [2048,128] f32, beta_raw: [1] f32, out: [65536] f32
//
// R7 design: WAVE-PRIVATE staging -> barrier-free main loop.
// Points are partitioned across the block's 4 waves (each wave owns 512 pts);
// each wave stages only its own tiles via global_load_lds into a private LDS
// region, so no __syncthreads is needed in the K-loop -- only a wave-local
// s_waitcnt vmcnt(0) lgkmcnt(0) (imm 0x0070). Rows are SHARED: every wave
// processes all 128 block rows (8 row-tiles of A in regs, 8 MFMAs per B
// fragment), partial mins combined across waves through LDS at the end.
// fp8 e4m3 mfma_scale_f32_16x16x128 (K=128 in one MFMA, scales=1.0).

#define NROWS 65536
#define NPTS  2048
#define DIMS  128
#define LOG1000F 6.9077542789816375f
#define STAGE_PTS 256
#define NSTAGES (NPTS / STAGE_PTS)   // 8

typedef __attribute__((ext_vector_type(8))) int i32x8;
typedef __attribute__((ext_vector_type(4))) float f32x4;

union AFrag { int d[8]; i32x8 v; };
union BFrag { uint4 u4[2]; i32x8 v; };

// --- pre-kernel: points f32 -> fp8 e4m3 in ws, plus ||p||^2 -----------------
__global__ __launch_bounds__(256) void prep_points_kernel(
    const float* __restrict__ pts, unsigned char* __restrict__ ptsf8,
    float* __restrict__ pnorm)
{
    int tid  = threadIdx.x;
    int lane = tid & 63;
    int w    = tid >> 6;
    int pt   = blockIdx.x * 4 + w;            // one wave per point
    const float2 v = *reinterpret_cast<const float2*>(
        pts + (size_t)pt * DIMS + lane * 2);  // 2 features per lane
    int pk = __builtin_amdgcn_cvt_pk_fp8_f32(v.x, v.y, 0, false);
    *reinterpret_cast<unsigned short*>(ptsf8 + (size_t)pt * DIMS + lane * 2) =
        (unsigned short)(pk & 0xFFFF);
    float ss = v.x * v.x + v.y * v.y;
    ss += __shfl_xor(ss, 1, 64);
    ss += __shfl_xor(ss, 2, 64);
    ss += __shfl_xor(ss, 4, 64);
    ss += __shfl_xor(ss, 8, 64);
    ss += __shfl_xor(ss, 16, 64);
    ss += __shfl_xor(ss, 32, 64);
    if (lane == 0) pnorm[pt] = ss;
}

// --- main kernel ------------------------------------------------------------
// grid: NROWS/128 = 512 blocks x 256 threads (4 waves); block owns 128 rows;
// wave owns the full 128 rows x a 512-point partition.
__global__ __launch_bounds__(256, 2) void distnet_main_kernel(
    const float* __restrict__ x, const unsigned char* __restrict__ ptsf8,
    const float* __restrict__ pnorm, const float* __restrict__ beta_raw,
    float* __restrict__ out)
{
    // stage: 256 pts x 128 B = 32 KB; unit (tt*2+c)*64 + lane (16 B each);
    // wave w's private region: tt in {4w..4w+3} -- disjoint across waves.
    __shared__ uint4 s_b[2][STAGE_PTS * DIMS / 16];   // 2 x 32 KB
    __shared__ float s_pn[NPTS];                      // 8 KB
    __shared__ float s_xn[128];                       // 0.5 KB
    __shared__ float s_part[4 * 128];                 // 2 KB partial mins

    int tid  = threadIdx.x;
    int wave = tid >> 6;
    int lane = tid & 63;
    int m    = lane & 15;          // A row / B col (point) index
    int q    = lane >> 4;          // k-quad: lane covers k = q*32 .. q*32+31
    int r0   = blockIdx.x * 128;   // block base row

    // Async staging of wave-private tiles: wave w stages tiles {4w..4w+3},
    // halves c=0,1 -> 8 x 1KB loads. Lane src: p = s*256 + tt*16 + m,
    // byte = p*128 + q*32 + c*16. LDS dst: uniform &s_b[buf][(tt*2+c)*64].
    const unsigned char* gbase = ptsf8;
    auto issue_stage = [&](int s, int buf) {
#pragma unroll
        for (int i = 0; i < 8; ++i) {
            int tt = wave * 4 + (i >> 1);
            int c  = i & 1;
            size_t pbyte = (size_t)(s * STAGE_PTS + tt * 16 + m) * DIMS
                           + (size_t)q * 32 + (size_t)c * 16;
            const void* g = gbase + pbyte;
            void* l = (void*)&s_b[buf][(tt * 2 + c) * 64];
            __builtin_amdgcn_global_load_lds(
                (const __attribute__((address_space(1))) unsigned int*)g,
                (__attribute__((address_space(3))) unsigned int*)l,
                16, 0, 0);
        }
    };

    issue_stage(0, 0);   // overlap with A-frag setup below

    for (int i = tid; i < NPTS / 4; i += 256)
        *reinterpret_cast<float4*>(&s_pn[i * 4]) =
            reinterpret_cast<const float4*>(pnorm)[i];

    // A fragments: 8 row-tiles (all 128 block rows); lane holds
    // A[m][k=q*32+j], j=0..31 (32 B fp8 = 8 VGPRs per tile).
    AFrag afrag[8];
#pragma unroll
    for (int t = 0; t < 8; ++t) {
        const float* xp = x + (size_t)(r0 + t * 16 + m) * DIMS + q * 32;
        float ss = 0.f;
#pragma unroll
        for (int d = 0; d < 8; ++d) {
            float4 v = *reinterpret_cast<const float4*>(xp + d * 4);
            int w0 = __builtin_amdgcn_cvt_pk_fp8_f32(v.x, v.y, 0, false);
            w0 = __builtin_amdgcn_cvt_pk_fp8_f32(v.z, v.w, w0, true);
            afrag[t].d[d] = w0;
            ss += v.x * v.x + v.y * v.y + v.z * v.z + v.w * v.w;
        }
        ss += __shfl_xor(ss, 16, 64);
        ss += __shfl_xor(ss, 32, 64);
        if (wave == 0 && lane < 16) s_xn[t * 16 + lane] = ss;
    }
    __syncthreads();   // s_pn / s_xn ready (stage-0 loads are wave-private)

    // runmin tracks min over this wave's points of (||p||^2 - 2 x.p).
    float runmin[8][4];
#pragma unroll
    for (int t = 0; t < 8; ++t)
#pragma unroll
        for (int r = 0; r < 4; ++r) runmin[t][r] = 1e30f;

    for (int s = 0; s < NSTAGES; ++s) {
        // Wave-local drain: stage-s loads done (vmcnt) AND all ds_reads of
        // the buffer about to be overwritten have returned (lgkmcnt).
        __builtin_amdgcn_s_waitcnt(0x0070);   // vmcnt(0) lgkmcnt(0)
        if (s + 1 < NSTAGES) issue_stage(s + 1, (s + 1) & 1);

        const uint4* bbuf = &s_b[s & 1][0];
#pragma unroll
        for (int tl = 0; tl < 4; ++tl) {
            int tt = wave * 4 + tl;
            BFrag bf;
            bf.u4[0] = bbuf[(tt * 2 + 0) * 64 + lane];   // ds_read_b128
            bf.u4[1] = bbuf[(tt * 2 + 1) * 64 + lane];
            float pn = s_pn[s * STAGE_PTS + tt * 16 + m]; // ds_read_b32
#pragma unroll
            for (int t = 0; t < 8; ++t) {
                f32x4 acc = {0.f, 0.f, 0.f, 0.f};
                acc = __builtin_amdgcn_mfma_scale_f32_16x16x128_f8f6f4(
                    afrag[t].v, bf.v, acc, 0, 0, 0,
                    0x7F7F7F7F, 0, 0x7F7F7F7F);
#pragma unroll
                for (int r = 0; r < 4; ++r)
                    runmin[t][r] = fminf(runmin[t][r],
                                         fmaf(-2.f, acc[r], pn));
            }
        }
    }

    // Per-wave lane reduce (min over the 16 cols), write partials to LDS.
    // C/D layout: col = m, row_local = t*16 + q*4 + r.
#pragma unroll
    for (int t = 0; t < 8; ++t) {
#pragma unroll
        for (int r = 0; r < 4; ++r) {
            float v = runmin[t][r];
            v = fminf(v, __shfl_xor(v, 1, 64));
            v = fminf(v, __shfl_xor(v, 2, 64));
            v = fminf(v, __shfl_xor(v, 4, 64));
            v = fminf(v, __shfl_xor(v, 8, 64));
            if (m == 0) s_part[wave * 128 + t * 16 + q * 4 + r] = v;
        }
    }
    __syncthreads();

    // Combine the 4 wave partitions, finish d^2, sigmoid, store.
    if (tid < 128) {
        float v = fminf(fminf(s_part[tid], s_part[128 + tid]),
                        fminf(s_part[256 + tid], s_part[384 + tid]));
        float xnv = s_xn[tid];
        float d2  = fmaxf(xnv + v, 0.f);
        float br    = beta_raw[0];
        float beta  = log1pf(expf(br));
        float alpha = -beta * LOG1000F;
        float z = (d2 + alpha) / beta;
        out[r0 + tid] = 1.f / (1.f + expf(-z));
    }
}

extern "C" void kernel_launch(void* const* d_in, const int* in_sizes, int n_in,
                              void* d_out, int out_size, void* d_ws, size_t ws_size,
                              hipStream_t stream) {
    const float* x        = (const float*)d_in[0];
    const float* pts      = (const float*)d_in[1];
    const float* beta_raw = (const float*)d_in[2];
    float* out            = (float*)d_out;

    unsigned char* ptsf8 = (unsigned char*)d_ws;                    // 256 KB
    float* pnorm = (float*)((char*)d_ws + (size_t)NPTS * DIMS);     // 8 KB

    prep_points_kernel<<<NPTS / 4, 256, 0, stream>>>(pts, ptsf8, pnorm);
    distnet_main_kernel<<<NROWS / 128, 256, 0, stream>>>(x, ptsf8, pnorm,
                                                         beta_raw, out);
}